// Round 1
// baseline (3263.300 us; speedup 1.0000x reference)
//
#include <hip/hip_runtime.h>
#include <hip/hip_bf16.h>
#include <math.h>

// ---------------------------------------------------------------------------
// Sent_Posit_Drmm_Modeler: round 1 — correctness-first fp32 implementation.
//
// Pipeline:
//  K0 k_qconv      : conv+sigmoid+residual for the 32 question rows -> ws
//  K1 k_qnorm      : norms^2 of q_emb / q_conv rows -> ws
//  K2 k_dconv_sims : per 64 doc rows: gather, conv (lanes=rows, waves split
//                    75 oc each, acc[75] in VGPRs), sigmoid+residual,
//                    norms via LDS atomics, then fused cosine sims vs all
//                    32 q rows (insens + sens) -> sim buffers [d][32] in ws
//  K3 k_pool       : 96 blocks (3 sim types x 32 q): top-5 over D=65536
//                    (thread-local sorted insert -> wave butterfly merge ->
//                    thread-0 merge) -> feats[32][6]
//  K4 k_head       : tiny MLP + sigmoid mean + BCE loss -> out[2] = {loss, emit}
//
// Conv semantics (padding=3, keep last L): out[t] = sum_k w[:,:,k] . x[t+1+k],
// rows beyond L-1 are zero. Verified against lax.conv_general_dilated.
// ---------------------------------------------------------------------------

#define E 300
#define D_ROWS 65536
#define Q_ROWS 32
#define CHUNKS 75   // 300 / 4

__device__ __forceinline__ float4 ld4(const float* p) { return *(const float4*)p; }
__device__ __forceinline__ float sigmoidf_(float x) { return 1.0f / (1.0f + __expf(-x)); }

__device__ __forceinline__ unsigned short f2bf(float f) {
    unsigned int u = __float_as_uint(f);
    unsigned int r = (u + 0x7fffu + ((u >> 16) & 1u)) >> 16;
    return (unsigned short)r;
}
__device__ __forceinline__ float bf2f(unsigned int us) {
    return __uint_as_float(us << 16);
}

// ---------------------------------------------------------------------------
// K0: question conv (32 rows). 5 blocks x 256 thr; block b covers oc [b*60,b*60+60),
// wave w covers 15 oc. Lanes 0..31 = rows.
// ---------------------------------------------------------------------------
__global__ __launch_bounds__(256, 2)
void k_qconv(const int* __restrict__ question, const float* __restrict__ embeds,
             const float* __restrict__ conv_w, const float* __restrict__ conv_b,
             float* __restrict__ q_conv)
{
    const int tid  = threadIdx.x;
    const int lane = tid & 63;
    const int w    = tid >> 6;
    const int ocb  = blockIdx.x * 60 + w * 15;
    if (lane >= Q_ROWS) return;
    const int g = lane;

    const int qid0 = question[g];
    const bool ok1 = (g + 1 < Q_ROWS), ok2 = (g + 2 < Q_ROWS), ok3 = (g + 3 < Q_ROWS);
    const float* e1 = embeds + (size_t)(ok1 ? question[g + 1] : 0) * E;
    const float* e2 = embeds + (size_t)(ok2 ? question[g + 2] : 0) * E;
    const float* e3 = embeds + (size_t)(ok3 ? question[g + 3] : 0) * E;

    float acc[15];
#pragma unroll
    for (int j = 0; j < 15; ++j) acc[j] = conv_b[ocb + j];

    for (int c = 0; c < CHUNKS; ++c) {
        const int ic0 = c * 4;
        float4 x1 = ok1 ? ld4(e1 + ic0) : make_float4(0.f, 0.f, 0.f, 0.f);
        float4 x2 = ok2 ? ld4(e2 + ic0) : make_float4(0.f, 0.f, 0.f, 0.f);
        float4 x3 = ok3 ? ld4(e3 + ic0) : make_float4(0.f, 0.f, 0.f, 0.f);
        const float* wb = conv_w + (size_t)ic0 * 3;
#pragma unroll
        for (int j = 0; j < 15; ++j) {
            const float4* wp = (const float4*)(wb + (size_t)(ocb + j) * 900);
            float4 w0 = wp[0], w1 = wp[1], w2 = wp[2];
            acc[j] += w0.x*x1.x + w0.y*x2.x + w0.z*x3.x + w0.w*x1.y
                    + w1.x*x2.y + w1.y*x3.y + w1.z*x1.z + w1.w*x2.z
                    + w2.x*x3.z + w2.y*x1.w + w2.z*x2.w + w2.w*x3.w;
        }
    }

    const float* e0 = embeds + (size_t)qid0 * E;
#pragma unroll
    for (int j = 0; j < 15; ++j) {
        float v = sigmoidf_(acc[j]) + e0[ocb + j];
        q_conv[g * E + ocb + j] = v;
    }
}

// ---------------------------------------------------------------------------
// K1: q norms^2. 1 block x 64 thr. qn2[0..31] = |q_emb|^2, [32..63] = |q_conv|^2.
// ---------------------------------------------------------------------------
__global__ void k_qnorm(const int* __restrict__ question, const float* __restrict__ embeds,
                        const float* __restrict__ q_conv, float* __restrict__ qn2)
{
    const int l = threadIdx.x;
    const int r = l & 31;
    const float* src = (l < 32) ? (embeds + (size_t)question[r] * E) : (q_conv + r * E);
    float s = 0.f;
    for (int c = 0; c < CHUNKS; ++c) {
        float4 v = ld4(src + 4 * c);
        s += v.x*v.x + v.y*v.y + v.z*v.z + v.w*v.w;
    }
    qn2[l] = s;
}

// ---------------------------------------------------------------------------
// K2: doc conv + fused sims. 1024 blocks x 256 thr; block = 64 doc rows.
// Conv: lanes = rows, wave w covers oc [w*75, w*75+75), acc[75] in VGPRs.
// Sims: wave 0/1 = insens q 0..15 / 16..31, wave 2/3 = sens.
// ---------------------------------------------------------------------------
__global__ __launch_bounds__(256, 2)
void k_dconv_sims(const int* __restrict__ doc1, const int* __restrict__ question,
                  const float* __restrict__ embeds, const float* __restrict__ conv_w,
                  const float* __restrict__ conv_b, const float* __restrict__ q_conv,
                  const float* __restrict__ qn2, float* __restrict__ sim_e,
                  float* __restrict__ sim_c)
{
    __shared__ __align__(16) unsigned short ysh[64 * E];  // conv rows, bf16 (38.4 KB)
    __shared__ float nde[64], ndc[64];

    const int tid  = threadIdx.x;
    const int lane = tid & 63;
    const int w    = tid >> 6;
    const int t0   = blockIdx.x * 64;
    const int g    = t0 + lane;

    if (tid < 64) { nde[tid] = 0.f; ndc[tid] = 0.f; }
    __syncthreads();

    // ---- conv phase ----
    const int ocb  = w * 75;
    const int vid0 = doc1[g];
    const bool ok1 = (g + 1 < D_ROWS), ok2 = (g + 2 < D_ROWS), ok3 = (g + 3 < D_ROWS);
    const int vid1 = ok1 ? doc1[g + 1] : 0;
    const int vid2 = ok2 ? doc1[g + 2] : 0;
    const int vid3 = ok3 ? doc1[g + 3] : 0;
    const float* e1 = embeds + (size_t)vid1 * E;
    const float* e2 = embeds + (size_t)vid2 * E;
    const float* e3 = embeds + (size_t)vid3 * E;

    float acc[75];
#pragma unroll
    for (int j = 0; j < 75; ++j) acc[j] = conv_b[ocb + j];

    for (int c = 0; c < CHUNKS; ++c) {
        const int ic0 = c * 4;
        float4 x1 = ok1 ? ld4(e1 + ic0) : make_float4(0.f, 0.f, 0.f, 0.f);
        float4 x2 = ok2 ? ld4(e2 + ic0) : make_float4(0.f, 0.f, 0.f, 0.f);
        float4 x3 = ok3 ? ld4(e3 + ic0) : make_float4(0.f, 0.f, 0.f, 0.f);
        const float* wb = conv_w + (size_t)ic0 * 3;
#pragma unroll
        for (int j = 0; j < 75; ++j) {
            const float4* wp = (const float4*)(wb + (size_t)(ocb + j) * 900);
            float4 w0 = wp[0], w1 = wp[1], w2 = wp[2];
            acc[j] += w0.x*x1.x + w0.y*x2.x + w0.z*x3.x + w0.w*x1.y
                    + w1.x*x2.y + w1.y*x3.y + w1.z*x1.z + w1.w*x2.z
                    + w2.x*x3.z + w2.y*x1.w + w2.z*x2.w + w2.w*x3.w;
        }
    }

    // ---- epilogue: sigmoid + residual, stash bf16 row, norms ----
    const float* e0 = embeds + (size_t)vid0 * E;
    float sq_c = 0.f, sq_e = 0.f;
#pragma unroll
    for (int j = 0; j < 75; ++j) {
        float x0 = e0[ocb + j];
        float v  = sigmoidf_(acc[j]) + x0;
        ysh[lane * E + ocb + j] = f2bf(v);
        sq_c += v * v;
        sq_e += x0 * x0;
    }
    atomicAdd(&ndc[lane], sq_c);
    atomicAdd(&nde[lane], sq_e);
    __syncthreads();

    // ---- sims phase ----
    const int ty = w >> 1;           // 0 = insens (emb), 1 = sens (conv)
    const int q0 = (w & 1) * 16;
    const float* Bb[16];
#pragma unroll
    for (int qj = 0; qj < 16; ++qj) {
        const int q = q0 + qj;
        Bb[qj] = (ty == 0) ? (embeds + (size_t)question[q] * E) : (q_conv + q * E);
    }
    float acc2[16];
#pragma unroll
    for (int qj = 0; qj < 16; ++qj) acc2[qj] = 0.f;

    const unsigned short* yrow = ysh + lane * E;
    for (int c = 0; c < CHUNKS; ++c) {
        const int ic0 = c * 4;
        float4 a;
        if (ty == 0) {
            a = ld4(e0 + ic0);
        } else {
            uint2 pk = *(const uint2*)(yrow + ic0);
            a.x = bf2f(pk.x & 0xffffu);
            a.y = bf2f(pk.x >> 16);
            a.z = bf2f(pk.y & 0xffffu);
            a.w = bf2f(pk.y >> 16);
        }
#pragma unroll
        for (int qj = 0; qj < 16; ++qj) {
            float4 b = ld4(Bb[qj] + ic0);
            acc2[qj] += a.x*b.x + a.y*b.y + a.z*b.z + a.w*b.w;
        }
    }

    const float invA = rsqrtf(ty == 0 ? nde[lane] : ndc[lane]);
    float* dst = (ty == 0 ? sim_e : sim_c) + (size_t)g * 32;
#pragma unroll
    for (int qj = 0; qj < 16; ++qj) {
        const int q = q0 + qj;
        dst[q] = acc2[qj] * invA * rsqrtf(qn2[ty * 32 + q]);
    }
}

// ---------------------------------------------------------------------------
// K3: top-5 pooling. 96 blocks (ty*32+q) x 256 thr.
// ---------------------------------------------------------------------------
#define TOP5_INS(v) do { float _v = (v); if (_v > t4v) {                     \
    if (_v > t2v) {                                                          \
        if (_v > t0v)      { t4v=t3v; t3v=t2v; t2v=t1v; t1v=t0v; t0v=_v; }   \
        else if (_v > t1v) { t4v=t3v; t3v=t2v; t2v=t1v; t1v=_v; }            \
        else               { t4v=t3v; t3v=t2v; t2v=_v; }                     \
    } else if (_v > t3v)   { t4v=t3v; t3v=_v; }                              \
    else                   { t4v=_v; } } } while (0)

__global__ void k_pool(const float* __restrict__ doc1_sim, const float* __restrict__ sim_e,
                       const float* __restrict__ sim_c, float* __restrict__ feats)
{
    const int ty = blockIdx.x >> 5;
    const int q  = blockIdx.x & 31;
    const float* src = (ty == 0) ? doc1_sim : (ty == 1 ? sim_e : sim_c);
    const int tid = threadIdx.x;

    float t0v = -1e30f, t1v = -1e30f, t2v = -1e30f, t3v = -1e30f, t4v = -1e30f;
    for (int d = tid; d < D_ROWS; d += 256) {
        TOP5_INS(src[(size_t)d * 32 + q]);
    }
    // butterfly merge inside the wave
    for (int m = 1; m < 64; m <<= 1) {
        float o0 = __shfl_xor(t0v, m), o1 = __shfl_xor(t1v, m), o2 = __shfl_xor(t2v, m),
              o3 = __shfl_xor(t3v, m), o4 = __shfl_xor(t4v, m);
        TOP5_INS(o0); TOP5_INS(o1); TOP5_INS(o2); TOP5_INS(o3); TOP5_INS(o4);
    }
    __shared__ float wt[4 * 5];
    if ((tid & 63) == 0) {
        const int wv = tid >> 6;
        wt[wv * 5 + 0] = t0v; wt[wv * 5 + 1] = t1v; wt[wv * 5 + 2] = t2v;
        wt[wv * 5 + 3] = t3v; wt[wv * 5 + 4] = t4v;
    }
    __syncthreads();
    if (tid == 0) {
        // thread 0 already holds wave 0's list; merge waves 1..3
        for (int i = 5; i < 20; ++i) TOP5_INS(wt[i]);
        feats[q * 6 + ty * 2 + 0] = t0v;
        feats[q * 6 + ty * 2 + 1] = (t0v + t1v + t2v + t3v + t4v) * 0.2f;
    }
}

// ---------------------------------------------------------------------------
// K4: head MLP + loss. 1 block x 64 thr.
// ---------------------------------------------------------------------------
__global__ void k_head(const float* __restrict__ feats, const float* __restrict__ W1,
                       const float* __restrict__ b1, const float* __restrict__ W2,
                       const float* __restrict__ b2, const float* __restrict__ a1,
                       const float* __restrict__ target, float* __restrict__ out)
{
    const int l = threadIdx.x;
    float s = 0.f;
    if (l < 32) {
        float f[6];
#pragma unroll
        for (int i = 0; i < 6; ++i) f[i] = feats[l * 6 + i];
        const float alpha = a1[0];
        float z = b2[0];
#pragma unroll
        for (int j = 0; j < 8; ++j) {
            float h = b1[j];
#pragma unroll
            for (int i = 0; i < 6; ++i) h += f[i] * W1[j * 6 + i];
            h = (h > 0.f) ? h : alpha * h;
            z += h * W2[j];
        }
        s = 1.f / (1.f + expf(-z));
    }
#pragma unroll
    for (int off = 16; off > 0; off >>= 1) s += __shfl_down(s, off, 64);
    if (l == 0) {
        const float emit = s * (1.0f / 32.0f);
        const float t = target[0];
        const float lsp = -log1pf(expf(-emit));   // log sigmoid(x)
        const float lsn = -log1pf(expf(emit));    // log sigmoid(-x)
        out[0] = -(t * lsp + (1.f - t) * lsn);
        out[1] = emit;
    }
}

// ---------------------------------------------------------------------------
extern "C" void kernel_launch(void* const* d_in, const int* in_sizes, int n_in,
                              void* d_out, int out_size, void* d_ws, size_t ws_size,
                              hipStream_t stream)
{
    const int*   doc1     = (const int*)d_in[0];
    const int*   question = (const int*)d_in[1];
    const float* doc1_sim = (const float*)d_in[2];
    const float* target   = (const float*)d_in[3];
    const float* embeds   = (const float*)d_in[4];
    const float* conv_w   = (const float*)d_in[5];
    const float* conv_b   = (const float*)d_in[6];
    const float* W1       = (const float*)d_in[7];
    const float* b1       = (const float*)d_in[8];
    const float* W2       = (const float*)d_in[9];
    const float* b2       = (const float*)d_in[10];
    const float* a1       = (const float*)d_in[11];
    // a2 (d_in[12]) unused in eval path

    float* out = (float*)d_out;
    float* ws  = (float*)d_ws;

    float* q_conv = ws;                    // 32*300   = 9600
    float* qn2    = ws + 9600;             // 64
    float* feats  = ws + 9664;             // 192
    float* sim_e  = ws + 10240;            // 65536*32 = 2097152
    float* sim_c  = sim_e + 2097152;       // 65536*32
    // total ws: ~16.8 MB

    k_qconv<<<5, 256, 0, stream>>>(question, embeds, conv_w, conv_b, q_conv);
    k_qnorm<<<1, 64, 0, stream>>>(question, embeds, q_conv, qn2);
    k_dconv_sims<<<1024, 256, 0, stream>>>(doc1, question, embeds, conv_w, conv_b,
                                           q_conv, qn2, sim_e, sim_c);
    k_pool<<<96, 256, 0, stream>>>(doc1_sim, sim_e, sim_c, feats);
    k_head<<<1, 64, 0, stream>>>(feats, W1, b1, W2, b2, a1, target, out);
}

// Round 2
// 1080.134 us; speedup vs baseline: 3.0212x; 3.0212x over previous
//
#include <hip/hip_runtime.h>
#include <hip/hip_bf16.h>
#include <math.h>

// ---------------------------------------------------------------------------
// Sent_Posit_Drmm_Modeler round 2: MFMA-based conv + fused sims.
//
//  K_gather : doc1 rows -> Xg bf16 [65539][320] (ic padded to 320, 3 zero rows)
//  K_wprep  : conv_w -> Wt bf16 [320 oc][960 kk], kk = t*320+ic (zero-padded)
//  K_qconv  : fp32 conv for 32 question rows (round-1 kernel, verified)
//  K_qprep  : Qe/Qc bf16 slabs [2][10][32][32] + qinv[2][32]
//  K_dnorm  : |Xg row| inverse norms
//  K_conv_sims (512 blocks x 512 thr):
//     P0: 30-step dbuf K-loop, global_load_lds(16B) staging,
//         mfma_f32_16x16x32_bf16, acc[4][5] per wave (2Mx4N wave grid)
//     P1: sigmoid+bias+residual -> LDS slabs [10][128][64B] + row-norm atomics
//     P2: sim_c GEMM (slabs x Qc) -> scaled cosine -> sim_c [d][32] f32
//     P3: restage Xg tile into slabs
//     P4: sim_e GEMM (slabs x Qe) -> sim_e
//  K_pool1/2: segmented coalesced top-5 -> feats;  K_head: MLP + BCE.
//
// Conv semantics (padding=3, keep last L): out[t] = sum_k w[:,:,k].x[t+1+k].
// Workspace use ~60 MB.
// ---------------------------------------------------------------------------

#define E 300
#define EP 320
#define D_ROWS 65536
#define DP_ROWS 65539
#define KK 960
#define KSTEPS 30
#define CHUNKS 75
#define Q_ROWS 32

typedef __attribute__((ext_vector_type(8))) short short8;
typedef __attribute__((ext_vector_type(4))) float f32x4;

__device__ __forceinline__ float4 ld4(const float* p) { return *(const float4*)p; }
__device__ __forceinline__ float sigmoidf_(float x) { return 1.0f / (1.0f + __expf(-x)); }

__device__ __forceinline__ unsigned short f2bf(float f) {
    unsigned int u = __float_as_uint(f);
    unsigned int r = (u + 0x7fffu + ((u >> 16) & 1u)) >> 16;
    return (unsigned short)r;
}
__device__ __forceinline__ float bf2f(unsigned int us) {
    return __uint_as_float(us << 16);
}

__device__ __forceinline__ void gload16(const void* g, void* l) {
    __builtin_amdgcn_global_load_lds((const __attribute__((address_space(1))) unsigned int*)g,
                                     (__attribute__((address_space(3))) unsigned int*)l,
                                     16, 0, 0);
}

// ---------------------------------------------------------------------------
// K_gather: Xg bf16 [DP_ROWS][EP]; rows >= D_ROWS and cols >= E are zero.
// ---------------------------------------------------------------------------
__global__ void k_gather(const int* __restrict__ doc1, const float* __restrict__ embeds,
                         unsigned int* __restrict__ Xg)
{
    int idx = blockIdx.x * blockDim.x + threadIdx.x;
    const int total = DP_ROWS * (EP / 2);
    const int stride = gridDim.x * blockDim.x;
    for (; idx < total; idx += stride) {
        int d = idx / 160;
        int j = idx - d * 160;
        int c0 = j * 2;
        unsigned int out = 0;
        if (d < D_ROWS) {
            const float* src = embeds + (size_t)doc1[d] * E;
            float v0 = (c0 < E) ? src[c0] : 0.f;
            float v1 = (c0 + 1 < E) ? src[c0 + 1] : 0.f;
            out = (unsigned int)f2bf(v0) | ((unsigned int)f2bf(v1) << 16);
        }
        Xg[idx] = out;
    }
}

// ---------------------------------------------------------------------------
// K_wprep: Wt[oc][kk] = conv_w[oc][ic][t], kk = t*320+ic, zero-padded.
// 600 blocks x 256 threads = 153600 dword pairs exactly.
// ---------------------------------------------------------------------------
__global__ void k_wprep(const float* __restrict__ conv_w, unsigned int* __restrict__ Wt)
{
    int idx = blockIdx.x * 256 + threadIdx.x;        // pair index, 0..153599
    int oc = idx / 480;
    int jj = idx - oc * 480;
    int kk = jj * 2;
    int t  = kk / EP;
    int ic = kk - t * EP;
    float v0 = 0.f, v1 = 0.f;
    if (oc < E) {
        if (ic < E)     v0 = conv_w[((size_t)oc * E + ic) * 3 + t];
        if (ic + 1 < E) v1 = conv_w[((size_t)oc * E + ic + 1) * 3 + t];
    }
    Wt[idx] = (unsigned int)f2bf(v0) | ((unsigned int)f2bf(v1) << 16);
}

// ---------------------------------------------------------------------------
// K_qconv: question conv (32 rows), fp32 — round-1 verified kernel.
// ---------------------------------------------------------------------------
__global__ __launch_bounds__(256, 2)
void k_qconv(const int* __restrict__ question, const float* __restrict__ embeds,
             const float* __restrict__ conv_w, const float* __restrict__ conv_b,
             float* __restrict__ q_conv)
{
    const int tid  = threadIdx.x;
    const int lane = tid & 63;
    const int w    = tid >> 6;
    const int ocb  = blockIdx.x * 60 + w * 15;
    if (lane >= Q_ROWS) return;
    const int g = lane;

    const int qid0 = question[g];
    const bool ok1 = (g + 1 < Q_ROWS), ok2 = (g + 2 < Q_ROWS), ok3 = (g + 3 < Q_ROWS);
    const float* e1 = embeds + (size_t)(ok1 ? question[g + 1] : 0) * E;
    const float* e2 = embeds + (size_t)(ok2 ? question[g + 2] : 0) * E;
    const float* e3 = embeds + (size_t)(ok3 ? question[g + 3] : 0) * E;

    float acc[15];
#pragma unroll
    for (int j = 0; j < 15; ++j) acc[j] = conv_b[ocb + j];

    for (int c = 0; c < CHUNKS; ++c) {
        const int ic0 = c * 4;
        float4 x1 = ok1 ? ld4(e1 + ic0) : make_float4(0.f, 0.f, 0.f, 0.f);
        float4 x2 = ok2 ? ld4(e2 + ic0) : make_float4(0.f, 0.f, 0.f, 0.f);
        float4 x3 = ok3 ? ld4(e3 + ic0) : make_float4(0.f, 0.f, 0.f, 0.f);
        const float* wb = conv_w + (size_t)ic0 * 3;
#pragma unroll
        for (int j = 0; j < 15; ++j) {
            const float4* wp = (const float4*)(wb + (size_t)(ocb + j) * 900);
            float4 w0 = wp[0], w1 = wp[1], w2 = wp[2];
            acc[j] += w0.x*x1.x + w0.y*x2.x + w0.z*x3.x + w0.w*x1.y
                    + w1.x*x2.y + w1.y*x3.y + w1.z*x1.z + w1.w*x2.z
                    + w2.x*x3.z + w2.y*x1.w + w2.z*x2.w + w2.w*x3.w;
        }
    }

    const float* e0 = embeds + (size_t)qid0 * E;
#pragma unroll
    for (int j = 0; j < 15; ++j) {
        float v = sigmoidf_(acc[j]) + e0[ocb + j];
        q_conv[g * E + ocb + j] = v;
    }
}

// ---------------------------------------------------------------------------
// K_qprep: Qs bf16 [2][10][32 q][32] slabs + qinv[2][32] (fp32 inverse norms).
// ---------------------------------------------------------------------------
__global__ void k_qprep(const int* __restrict__ question, const float* __restrict__ embeds,
                        const float* __restrict__ q_conv, unsigned short* __restrict__ Qs,
                        float* __restrict__ qinv)
{
    __shared__ float sums[2][32];
    const int tid = threadIdx.x;
    const int q = tid & 31, s0 = tid >> 5;
    if (tid < 64) sums[tid >> 5][tid & 31] = 0.f;
    __syncthreads();

    for (int ty = 0; ty < 2; ++ty) {
        const float* src = ty ? (q_conv + q * E) : (embeds + (size_t)question[q] * E);
        float acc = 0.f;
        for (int s = s0; s < 10; s += 8) {
            for (int j = 0; j < 32; ++j) {
                int c = s * 32 + j;
                float v = (c < E) ? src[c] : 0.f;
                acc += v * v;
                Qs[(((size_t)ty * 10 + s) * 32 + q) * 32 + j] = f2bf(v);
            }
        }
        atomicAdd(&sums[ty][q], acc);
    }
    __syncthreads();
    if (tid < 64) qinv[tid] = rsqrtf(sums[tid >> 5][tid & 31]);
}

// ---------------------------------------------------------------------------
// K_dnorm: one wave per row; dinv[d] = 1/|Xg row d|.
// ---------------------------------------------------------------------------
__global__ void k_dnorm(const unsigned int* __restrict__ Xg, float* __restrict__ dinv)
{
    const int row  = (blockIdx.x * 256 + threadIdx.x) >> 6;
    const int lane = threadIdx.x & 63;
    if (row >= D_ROWS) return;
    const unsigned int* p = Xg + (size_t)row * 160;
    float s = 0.f;
#pragma unroll
    for (int i = 0; i < 3; ++i) {
        int c = lane + i * 64;
        if (c < 160) {
            unsigned int u = p[c];
            float a = bf2f(u & 0xffffu), b = bf2f(u >> 16);
            s += a * a + b * b;
        }
    }
#pragma unroll
    for (int m = 32; m; m >>= 1) s += __shfl_xor(s, m);
    if (lane == 0) dinv[row] = rsqrtf(s);
}

// ---------------------------------------------------------------------------
// K_conv_sims: the fused MFMA kernel. 512 blocks x 512 threads.
// LDS: [0,57344) A/B double buffers during K-loop; [0,81920) slabs after;
//      [81920,82432) rowsum/rnorm.
// ---------------------------------------------------------------------------
__global__ __launch_bounds__(512, 2)
void k_conv_sims(const unsigned short* __restrict__ Xg,
                 const unsigned short* __restrict__ Wt,
                 const float* __restrict__ conv_b,
                 const unsigned short* __restrict__ Qs,
                 const float* __restrict__ qinv,
                 const float* __restrict__ dinv,
                 float* __restrict__ sim_e, float* __restrict__ sim_c)
{
    __shared__ __align__(16) char lds_raw[82432];
    float* rowsum = (float*)(lds_raw + 81920);

    const int tid = threadIdx.x;
    const int lane = tid & 63, wid = tid >> 6;
    const int lane15 = lane & 15, lhi = lane >> 4;
    const int d0 = blockIdx.x * 128;

    char* Ab0 = lds_raw;
    char* Ab1 = lds_raw + 8192;
    char* Bb0 = lds_raw + 16384;
    char* Bb1 = lds_raw + 16384 + 20480;

    const int m_base = (wid >> 2) * 64;
    const int n_base = (wid & 3) * 80;

    f32x4 acc[4][5];
#pragma unroll
    for (int mf = 0; mf < 4; ++mf)
#pragma unroll
        for (int nf = 0; nf < 5; ++nf) acc[mf][nf] = (f32x4)0.f;

    // ---- staging helper (s = K-step index, kk0 = 32*s) ----
    auto stageAB = [&](int s) {
        char* Ad = (s & 1) ? Ab1 : Ab0;
        char* Bd = (s & 1) ? Bb1 : Bb0;
        const int t  = s / 10;
        const int c0 = (s - t * 10) * 32;
        const int kk0 = s * 32;
        {   // A: one 1 KiB wave-instruction per wave; 16 rows x 64 B
            const int row = wid * 16 + (lane >> 2), chunk = lane & 3;
            gload16(Xg + (size_t)(d0 + 1 + t + row) * EP + c0 + chunk * 8,
                    Ad + wid * 1024);
        }
        for (int j = wid; j < 20; j += 8) {   // B: 20 wave-instructions
            const int n = j * 16 + (lane >> 2), chunk = lane & 3;
            gload16(Wt + (size_t)n * KK + kk0 + chunk * 8,
                    Bd + j * 1024);
        }
    };

    // ---- P0: K-loop ----
    stageAB(0);
    __syncthreads();
    for (int s = 0; s < KSTEPS; ++s) {
        if (s + 1 < KSTEPS) stageAB(s + 1);
        const char* Ac = (s & 1) ? Ab1 : Ab0;
        const char* Bc = (s & 1) ? Bb1 : Bb0;
        short8 a[4], b[5];
#pragma unroll
        for (int mf = 0; mf < 4; ++mf)
            a[mf] = *(const short8*)(Ac + (m_base + mf * 16 + lane15) * 64 + lhi * 16);
#pragma unroll
        for (int nf = 0; nf < 5; ++nf)
            b[nf] = *(const short8*)(Bc + (n_base + nf * 16 + lane15) * 64 + lhi * 16);
#pragma unroll
        for (int mf = 0; mf < 4; ++mf)
#pragma unroll
            for (int nf = 0; nf < 5; ++nf)
                acc[mf][nf] = __builtin_amdgcn_mfma_f32_16x16x32_bf16(a[mf], b[nf], acc[mf][nf], 0, 0, 0);
        __syncthreads();
    }

    // ---- P1: epilogue -> Y slabs [10][128 r][64 B] + row norms ----
    if (tid < 128) rowsum[tid] = 0.f;
    __syncthreads();
#pragma unroll
    for (int mf = 0; mf < 4; ++mf) {
#pragma unroll
        for (int reg = 0; reg < 4; ++reg) {
            const int r = m_base + mf * 16 + lhi * 4 + reg;
            float part = 0.f;
#pragma unroll
            for (int nf = 0; nf < 5; ++nf) {
                const int col = n_base + nf * 16 + lane15;
                float v = 0.f;
                if (col < E) {
                    float x0 = bf2f(Xg[(size_t)(d0 + r) * EP + col]);
                    v = sigmoidf_(acc[mf][nf][reg] + conv_b[col]) + x0;
                }
                part += v * v;
                *(unsigned short*)(lds_raw + (col >> 5) * 8192 + r * 64 + (col & 31) * 2) = f2bf(v);
            }
            atomicAdd(&rowsum[r], part);
        }
    }
    __syncthreads();
    if (tid < 128) rowsum[tid] = rsqrtf(rowsum[tid]);
    __syncthreads();

    // ---- P2: sim_c = cosine(Y, Qc) ----
    {
        const int m0 = wid * 16;
        f32x4 c2[2];
        c2[0] = (f32x4)0.f; c2[1] = (f32x4)0.f;
        for (int ks = 0; ks < 10; ++ks) {
            short8 av = *(const short8*)(lds_raw + ks * 8192 + (m0 + lane15) * 64 + lhi * 16);
#pragma unroll
            for (int nf = 0; nf < 2; ++nf) {
                short8 bq = *(const short8*)(Qs + (((size_t)10 + ks) * 32 + nf * 16 + lane15) * 32 + lhi * 8);
                c2[nf] = __builtin_amdgcn_mfma_f32_16x16x32_bf16(av, bq, c2[nf], 0, 0, 0);
            }
        }
#pragma unroll
        for (int nf = 0; nf < 2; ++nf) {
            const int q = nf * 16 + lane15;
            const float qi = qinv[32 + q];
#pragma unroll
            for (int reg = 0; reg < 4; ++reg) {
                const int r = m0 + lhi * 4 + reg;
                sim_c[(size_t)(d0 + r) * 32 + q] = c2[nf][reg] * rowsum[r] * qi;
            }
        }
    }
    __syncthreads();

    // ---- P3: restage Xg rows d0..d0+127 into slabs ----
    for (int j = wid; j < 80; j += 8) {
        const int ks = j >> 3, sub = j & 7;
        const int row = sub * 16 + (lane >> 2), chunk = lane & 3;
        gload16(Xg + (size_t)(d0 + row) * EP + ks * 32 + chunk * 8,
                lds_raw + j * 1024);
    }
    __syncthreads();

    // ---- P4: sim_e = cosine(Xg, Qe) ----
    {
        const int m0 = wid * 16;
        f32x4 c2[2];
        c2[0] = (f32x4)0.f; c2[1] = (f32x4)0.f;
        for (int ks = 0; ks < 10; ++ks) {
            short8 av = *(const short8*)(lds_raw + ks * 8192 + (m0 + lane15) * 64 + lhi * 16);
#pragma unroll
            for (int nf = 0; nf < 2; ++nf) {
                short8 bq = *(const short8*)(Qs + ((size_t)ks * 32 + nf * 16 + lane15) * 32 + lhi * 8);
                c2[nf] = __builtin_amdgcn_mfma_f32_16x16x32_bf16(av, bq, c2[nf], 0, 0, 0);
            }
        }
#pragma unroll
        for (int nf = 0; nf < 2; ++nf) {
            const int q = nf * 16 + lane15;
            const float qi = qinv[q];
#pragma unroll
            for (int reg = 0; reg < 4; ++reg) {
                const int r = m0 + lhi * 4 + reg;
                sim_e[(size_t)(d0 + r) * 32 + q] = c2[nf][reg] * dinv[d0 + r] * qi;
            }
        }
    }
}

// ---------------------------------------------------------------------------
// K_pool1: segmented top-5. 96 blocks (3 ty x 32 seg) x 256 thr.
// ---------------------------------------------------------------------------
#define TOP5_INS(v) do { float _v = (v); if (_v > t4v) {                     \
    if (_v > t2v) {                                                          \
        if (_v > t0v)      { t4v=t3v; t3v=t2v; t2v=t1v; t1v=t0v; t0v=_v; }   \
        else if (_v > t1v) { t4v=t3v; t3v=t2v; t2v=t1v; t1v=_v; }            \
        else               { t4v=t3v; t3v=t2v; t2v=_v; }                     \
    } else if (_v > t3v)   { t4v=t3v; t3v=_v; }                              \
    else                   { t4v=_v; } } } while (0)

__global__ void k_pool1(const float* __restrict__ doc1_sim, const float* __restrict__ sim_e,
                        const float* __restrict__ sim_c, float* __restrict__ part)
{
    const int ty  = blockIdx.x >> 5;
    const int seg = blockIdx.x & 31;
    const float* src = (ty == 0) ? doc1_sim : (ty == 1 ? sim_e : sim_c);
    const int tid = threadIdx.x, q = tid & 31, stripe = tid >> 5;

    float t0v = -3e38f, t1v = -3e38f, t2v = -3e38f, t3v = -3e38f, t4v = -3e38f;
    const size_t base = (size_t)seg * 2048 * 32 + q;
    for (int i = 0; i < 256; ++i) {
        TOP5_INS(src[base + (size_t)(stripe + i * 8) * 32]);
    }
    __shared__ float wt[256 * 5];
    wt[tid * 5 + 0] = t0v; wt[tid * 5 + 1] = t1v; wt[tid * 5 + 2] = t2v;
    wt[tid * 5 + 3] = t3v; wt[tid * 5 + 4] = t4v;
    __syncthreads();
    if (stripe == 0) {
        for (int s2 = 1; s2 < 8; ++s2)
            for (int k = 0; k < 5; ++k) TOP5_INS(wt[(s2 * 32 + q) * 5 + k]);
        float* dst = part + ((size_t)(ty * 32 + seg) * 32 + q) * 5;
        dst[0] = t0v; dst[1] = t1v; dst[2] = t2v; dst[3] = t3v; dst[4] = t4v;
    }
}

// ---------------------------------------------------------------------------
// K_pool2: merge 32 segments per (ty, q) -> feats[32][6].
// ---------------------------------------------------------------------------
__global__ void k_pool2(const float* __restrict__ part, float* __restrict__ feats)
{
    const int tid = threadIdx.x;
    if (tid >= 96) return;
    const int ty = tid >> 5, q = tid & 31;
    float t0v = -3e38f, t1v = -3e38f, t2v = -3e38f, t3v = -3e38f, t4v = -3e38f;
    for (int seg = 0; seg < 32; ++seg) {
        const float* p = part + ((size_t)(ty * 32 + seg) * 32 + q) * 5;
        for (int k = 0; k < 5; ++k) TOP5_INS(p[k]);
    }
    feats[q * 6 + ty * 2 + 0] = t0v;
    feats[q * 6 + ty * 2 + 1] = (t0v + t1v + t2v + t3v + t4v) * 0.2f;
}

// ---------------------------------------------------------------------------
// K_head: tiny MLP + sigmoid mean + BCE. (round-1 verified)
// ---------------------------------------------------------------------------
__global__ void k_head(const float* __restrict__ feats, const float* __restrict__ W1,
                       const float* __restrict__ b1, const float* __restrict__ W2,
                       const float* __restrict__ b2, const float* __restrict__ a1,
                       const float* __restrict__ target, float* __restrict__ out)
{
    const int l = threadIdx.x;
    float s = 0.f;
    if (l < 32) {
        float f[6];
#pragma unroll
        for (int i = 0; i < 6; ++i) f[i] = feats[l * 6 + i];
        const float alpha = a1[0];
        float z = b2[0];
#pragma unroll
        for (int j = 0; j < 8; ++j) {
            float h = b1[j];
#pragma unroll
            for (int i = 0; i < 6; ++i) h += f[i] * W1[j * 6 + i];
            h = (h > 0.f) ? h : alpha * h;
            z += h * W2[j];
        }
        s = 1.f / (1.f + expf(-z));
    }
#pragma unroll
    for (int off = 16; off > 0; off >>= 1) s += __shfl_down(s, off, 64);
    if (l == 0) {
        const float emit = s * (1.0f / 32.0f);
        const float t = target[0];
        const float lsp = -log1pf(expf(-emit));
        const float lsn = -log1pf(expf(emit));
        out[0] = -(t * lsp + (1.f - t) * lsn);
        out[1] = emit;
    }
}

// ---------------------------------------------------------------------------
extern "C" void kernel_launch(void* const* d_in, const int* in_sizes, int n_in,
                              void* d_out, int out_size, void* d_ws, size_t ws_size,
                              hipStream_t stream)
{
    const int*   doc1     = (const int*)d_in[0];
    const int*   question = (const int*)d_in[1];
    const float* doc1_sim = (const float*)d_in[2];
    const float* target   = (const float*)d_in[3];
    const float* embeds   = (const float*)d_in[4];
    const float* conv_w   = (const float*)d_in[5];
    const float* conv_b   = (const float*)d_in[6];
    const float* W1       = (const float*)d_in[7];
    const float* b1       = (const float*)d_in[8];
    const float* W2       = (const float*)d_in[9];
    const float* b2       = (const float*)d_in[10];
    const float* a1       = (const float*)d_in[11];

    float* out = (float*)d_out;
    float* ws  = (float*)d_ws;

    // ---- workspace layout (float offsets) ----
    float* q_conv = ws;                          // 9600
    float* qinv   = ws + 9600;                   // 64
    float* feats  = ws + 9664;                   // 192
    float* part   = ws + 9856;                   // 15360
    float* sim_e  = ws + 25600;                  // 2097152
    float* sim_c  = ws + 2122752;                // 2097152
    unsigned short* Xg = (unsigned short*)(ws + 4219904);   // 20,972,480 bf16
    float* Wt_f   = ws + 14706144;               // 153600 (307200 bf16)
    float* Qs_f   = ws + 14859744;               // 10240  (20480 bf16)
    float* dinv   = ws + 14869984;               // 65536   -> total ~59.8 MB
    unsigned short* Wt = (unsigned short*)Wt_f;
    unsigned short* Qs = (unsigned short*)Qs_f;

    k_gather<<<2048, 256, 0, stream>>>(doc1, embeds, (unsigned int*)Xg);
    k_wprep <<<600, 256, 0, stream>>>(conv_w, (unsigned int*)Wt);
    k_qconv <<<5, 256, 0, stream>>>(question, embeds, conv_w, conv_b, q_conv);
    k_qprep <<<1, 256, 0, stream>>>(question, embeds, q_conv, Qs, qinv);
    k_dnorm <<<16384, 256, 0, stream>>>((const unsigned int*)Xg, dinv);
    k_conv_sims<<<512, 512, 0, stream>>>(Xg, Wt, conv_b, Qs, qinv, dinv, sim_e, sim_c);
    k_pool1<<<96, 256, 0, stream>>>(doc1_sim, sim_e, sim_c, part);
    k_pool2<<<1, 128, 0, stream>>>(part, feats);
    k_head <<<1, 64, 0, stream>>>(feats, W1, b1, W2, b2, a1, target, out);
}